// Round 1
// baseline (94.735 us; speedup 1.0000x reference)
//
#include <hip/hip_runtime.h>

#define N 8192
#define FIN 256
#define FOUT 64
#define ALPHA 0.2f

typedef float f32x4 __attribute__((ext_vector_type(4)));
typedef short s16x4 __attribute__((ext_vector_type(4)));

static __device__ __forceinline__ unsigned short f2bf(float x) {
    // RNE float->bf16 (values are finite, no NaN handling needed)
    unsigned u = __float_as_uint(x);
    u += 0x7fffu + ((u >> 16) & 1u);
    return (unsigned short)(u >> 16);
}

// ---------------- Kernel 1: h = input@W + b_lin; write hT (bf16, [FOUT][N]), s1, s2 ----
__global__ __launch_bounds__(256) void k_linear(
    const float* __restrict__ input, const float* __restrict__ W,
    const float* __restrict__ b_lin, const float* __restrict__ a,
    unsigned short* __restrict__ hT, float* __restrict__ s1, float* __restrict__ s2)
{
    __shared__ float in_sh[32 * FIN];     // 32 KB
    __shared__ float hst[64][33];         // h staged transposed, pad 33 -> conflict-free
    int t = threadIdx.x;
    int i0 = blockIdx.x * 32;

    // stage 32 input rows (coalesced float4)
    const float4* gin = (const float4*)(input + (size_t)i0 * FIN);
    float4* lin = (float4*)in_sh;
#pragma unroll
    for (int m = 0; m < 8; m++) lin[m * 256 + t] = gin[m * 256 + t];

    int f = t & 63, g = t >> 6;           // g = wave id (4 waves), handles rows g*8..g*8+7
    float a1v = a[f], a2v = a[FOUT + f], blv = b_lin[f];
    __syncthreads();

    float h[8];
#pragma unroll
    for (int r = 0; r < 8; r++) h[r] = blv;
#pragma unroll 4
    for (int k = 0; k < FIN; k++) {
        float wv = W[k * FOUT + f];       // coalesced, L2-hot (W = 64 KB)
#pragma unroll
        for (int r = 0; r < 8; r++) h[r] += in_sh[(g * 8 + r) * FIN + k] * wv;
    }

#pragma unroll
    for (int r = 0; r < 8; r++) {
        hst[f][g * 8 + r] = h[r];
        float v1 = h[r] * a1v, v2 = h[r] * a2v;
#pragma unroll
        for (int d = 1; d < 64; d <<= 1) { v1 += __shfl_xor(v1, d); v2 += __shfl_xor(v2, d); }
        if (f == 0) { s1[i0 + g * 8 + r] = v1; s2[i0 + g * 8 + r] = v2; }
    }
    __syncthreads();

    // write hT tile: thread t -> feature fo, 8 consecutive i
    int fo = t >> 2, seg = t & 3;
    unsigned pk[4];
#pragma unroll
    for (int m = 0; m < 4; m++) {
        unsigned lo = f2bf(hst[fo][seg * 8 + 2 * m]);
        unsigned hi = f2bf(hst[fo][seg * 8 + 2 * m + 1]);
        pk[m] = lo | (hi << 16);
    }
    int4 v; v.x = (int)pk[0]; v.y = (int)pk[1]; v.z = (int)pk[2]; v.w = (int)pk[3];
    *(int4*)(hT + (size_t)fo * N + i0 + seg * 8) = v;
}

// ---------------- Kernel 2: global max of s2 (any m >= rowmax is valid for softmax) ----
__global__ __launch_bounds__(256) void k_s2max(const float* __restrict__ s2,
                                               float* __restrict__ s2max)
{
    __shared__ float red[4];
    int t = threadIdx.x;
    float m = -1e30f;
    for (int k = t; k < N; k += 256) m = fmaxf(m, s2[k]);
#pragma unroll
    for (int d = 1; d < 64; d <<= 1) m = fmaxf(m, __shfl_xor(m, d));
    if ((t & 63) == 0) red[t >> 6] = m;
    __syncthreads();
    if (t == 0) s2max[0] = fmaxf(fmaxf(red[0], red[1]), fmaxf(red[2], red[3]));
}

// ---------------- Kernel 3: fused mask + softmax(num/den) + P@H via MFMA --------------
// Grid: (N/64) * chunks blocks, 256 threads (4 waves, 16 rows/wave).
// chunk = bid & (chunks-1)  -> equals XCD id for chunks=8 (L2 locality for hT/s2 slice)
__global__ __launch_bounds__(256) void k_attn(
    const int* __restrict__ adj, const float* __restrict__ s1g,
    const float* __restrict__ s2g, const unsigned short* __restrict__ hT,
    const float* __restrict__ s2maxp, const float* __restrict__ bias,
    float* __restrict__ numP, float* __restrict__ denP, float* __restrict__ out,
    int log2c)
{
    extern __shared__ char smem[];
    unsigned short* tile = (unsigned short*)smem;            // [64][72] bf16 = 9216 B
    int clen = N >> log2c;
    float* s2sh = (float*)(smem + 9216);                     // clen floats
    float* densh = (float*)(smem + 9216 + (clen << 2));      // 64 floats (direct path)

    const float LOG2E = 1.4426950408889634f;
    int bid = blockIdx.x;
    int chunk = bid & ((1 << log2c) - 1);
    int rb = bid >> log2c;
    int jstart = chunk * clen;
    int t = threadIdx.x, w = t >> 6, l = t & 63;
    int l15 = l & 15, kg = l >> 4;

    // stage this chunk's s2 slice
    for (int idx = t; idx < (clen >> 2); idx += 256)
        ((float4*)s2sh)[idx] = ((const float4*)(s2g + jstart))[idx];

    int i0 = rb * 64;
    int i = i0 + w * 16 + l15;            // this lane's P-row (MFMA A layout: row = l&15)
    float s1v = s1g[i];
    float s2m = s2maxp[0];
    float mx = s1v + s2m; mx = fmaxf(mx, ALPHA * mx);   // leaky(s1+s2max) >= rowmax
    float m2 = mx * LOG2E;

    f32x4 acc[4] = {};
    float dacc = 0.f;
    const int4* adjrow = (const int4*)(adj + (size_t)i * N);
    __syncthreads();

    int iters = clen >> 6;
    for (int it = 0; it < iters; it++) {
        int j0 = it * 64;
        // stage hT tile [64 features][64 j] bf16, row stride 72 (pad kills bank conflicts)
#pragma unroll
        for (int m = 0; m < 2; m++) {
            int c = t + m * 256;
            int fr = c >> 3, off = (c & 7) * 8;
            *(int4*)(tile + fr * 72 + off) =
                *(const int4*)(hT + (size_t)fr * N + jstart + j0 + off);
        }
        // generate A fragments (P values) directly in mfma_16x16x16 A layout:
        // lane row = l&15, k = kg*4 + e within each 16-wide k-block
        s16x4 afr[4];
#pragma unroll
        for (int kb = 0; kb < 4; kb++) {
            int jloc = j0 + kb * 16 + kg * 4;
            int4 av = adjrow[(jstart + jloc) >> 2];
            float4 sv = *(const float4*)&s2sh[jloc];
            float p0, p1, p2, p3;
            { float x = s1v + sv.x; x = fmaxf(x, ALPHA * x); p0 = (av.x > 0) ? exp2f(x * LOG2E - m2) : 0.f; }
            { float x = s1v + sv.y; x = fmaxf(x, ALPHA * x); p1 = (av.y > 0) ? exp2f(x * LOG2E - m2) : 0.f; }
            { float x = s1v + sv.z; x = fmaxf(x, ALPHA * x); p2 = (av.z > 0) ? exp2f(x * LOG2E - m2) : 0.f; }
            { float x = s1v + sv.w; x = fmaxf(x, ALPHA * x); p3 = (av.w > 0) ? exp2f(x * LOG2E - m2) : 0.f; }
            dacc += (p0 + p1) + (p2 + p3);
            s16x4 af;
            af[0] = (short)f2bf(p0); af[1] = (short)f2bf(p1);
            af[2] = (short)f2bf(p2); af[3] = (short)f2bf(p3);
            afr[kb] = af;
        }
        __syncthreads();
#pragma unroll
        for (int nt = 0; nt < 4; nt++) {
#pragma unroll
            for (int kb = 0; kb < 4; kb++) {
                s16x4 bfr = *(const s16x4*)(tile + (nt * 16 + l15) * 72 + kb * 16 + kg * 4);
                acc[nt] = __builtin_amdgcn_mfma_f32_16x16x16bf16_1k(afr[kb], bfr, acc[nt], 0, 0, 0);
            }
        }
        __syncthreads();
    }

    // row denominators: lanes l, l+16, l+32, l+48 share row l&15
    dacc += __shfl_xor(dacc, 16);
    dacc += __shfl_xor(dacc, 32);

    if (log2c == 0) {
        // direct path: full j-range in one block -> normalize and write output here
        if (l < 16) densh[w * 16 + l] = dacc;
        __syncthreads();
#pragma unroll
        for (int nt = 0; nt < 4; nt++) {
#pragma unroll
            for (int r = 0; r < 4; r++) {
                int orow = w * 16 + kg * 4 + r;   // C layout: row=(l>>4)*4+reg, col=l&15
                out[(size_t)(i0 + orow) * FOUT + nt * 16 + l15] =
                    acc[nt][r] / densh[orow] + bias[nt * 16 + l15];
            }
        }
    } else {
        if (l < 16) denP[(size_t)chunk * N + i0 + w * 16 + l] = dacc;
#pragma unroll
        for (int nt = 0; nt < 4; nt++) {
#pragma unroll
            for (int r = 0; r < 4; r++) {
                int orow = w * 16 + kg * 4 + r;
                numP[((size_t)chunk * N + i0 + orow) * FOUT + nt * 16 + l15] = acc[nt][r];
            }
        }
    }
}

// ---------------- Kernel 4: combine chunk partials, divide, add bias ------------------
__global__ __launch_bounds__(256) void k_finalize(
    const float* __restrict__ numP, const float* __restrict__ denP,
    const float* __restrict__ bias, float* __restrict__ out, int chunks)
{
    int idx = blockIdx.x * 256 + threadIdx.x;
    int i = idx >> 6, f = idx & 63;
    float nsum = 0.f, dsum = 0.f;
    for (int c = 0; c < chunks; c++) {
        nsum += numP[(size_t)c * (N * FOUT) + idx];
        dsum += denP[(size_t)c * N + i];
    }
    out[idx] = nsum / dsum + bias[f];
}

extern "C" void kernel_launch(void* const* d_in, const int* in_sizes, int n_in,
                              void* d_out, int out_size, void* d_ws, size_t ws_size,
                              hipStream_t stream)
{
    const float* input = (const float*)d_in[0];
    const int*   adj   = (const int*)d_in[1];
    const float* W     = (const float*)d_in[2];
    const float* b_lin = (const float*)d_in[3];
    const float* a     = (const float*)d_in[4];
    const float* bias  = (const float*)d_in[5];
    float* out = (float*)d_out;

    char* ws = (char*)d_ws;
    unsigned short* hT = (unsigned short*)ws;                    // 1 MiB
    float* s1    = (float*)(ws + 1048576);                       // 32 KB
    float* s2    = (float*)(ws + 1048576 + 32768);               // 32 KB
    float* s2max = (float*)(ws + 1048576 + 65536);               // 4 B (padded)
    size_t fixed = 1048576 + 65536 + 256;

    int log2c = 3;                                               // prefer 8 chunks
    while (log2c > 0) {
        size_t need = (((size_t)N * FOUT + N) * 4u) << log2c;
        if (fixed + need <= ws_size) break;
        log2c--;
    }
    float* numP = (float*)(ws + fixed);
    float* denP = (float*)(ws + fixed + (((size_t)N * FOUT * 4) << log2c));

    hipLaunchKernelGGL(k_linear, dim3(256), dim3(256), 0, stream,
                       input, W, b_lin, a, hT, s1, s2);
    hipLaunchKernelGGL(k_s2max, dim3(1), dim3(256), 0, stream, s2, s2max);

    int clen = N >> log2c;
    size_t smem = 9216 + ((size_t)clen << 2) + 256;
    hipLaunchKernelGGL(k_attn, dim3(128 << log2c), dim3(256), smem, stream,
                       adj, s1, s2, hT, s2max, bias, numP, denP, out, log2c);
    if (log2c > 0)
        hipLaunchKernelGGL(k_finalize, dim3(2048), dim3(256), 0, stream,
                           numP, denP, bias, out, 1 << log2c);
}